// Round 1
// baseline (1080.957 us; speedup 1.0000x reference)
//
#include <hip/hip_runtime.h>
#include <math.h>

#define LL 32
#define BB 4
#define DD 64
#define NH 4
#define DKK 16
#define BN_INV 0.9999950000374997f

__device__ __forceinline__ float lrelu(float v){ return v > 0.f ? v : 0.01f*v; }

// ---- effective per-head K/V projection matrices: A[n][d][k] = sum_c conv1_w[n,(t+1)*64+c,d]*w{k,v}[n,c,k]
__global__ void k_eff(const float* __restrict__ c1w, const float* __restrict__ c1b,
                      const float* __restrict__ wk, const float* __restrict__ wv,
                      float* __restrict__ A, float* __restrict__ bf){
  int tid = blockIdx.x*256 + threadIdx.x;           // 16384 threads
  int k = tid & 15, d = (tid>>4)&63, n=(tid>>10)&3, t=(tid>>12)&1, i=tid>>13;
  const float* wsel = (t ? wv : wk) + (i*NH+n)*64*16;
  const float* cw   = c1w + ((i*NH+n)*192 + (t+1)*64)*64;
  float acc = 0.f;
  for(int c=0;c<64;++c) acc += cw[c*64+d]*wsel[c*16+k];
  A[tid] = acc;                                     // layout (((i*2+t)*4+n)*64+d)*16+k == tid
  if(d==0){
    const float* cb = c1b + (i*NH+n)*192 + (t+1)*64;
    float ba=0.f;
    for(int c=0;c<64;++c) ba += cb[c]*wsel[c*16+k];
    bf[((i*2+t)*4+n)*16+k] = ba;
  }
}

// ---- sinusoidal pos table: pos[l][d]
__global__ void k_pos(float* __restrict__ pos){
  int tid = blockIdx.x*256 + threadIdx.x;           // 2048
  int d = tid & 63, l = tid >> 6;
  float ex = (float)(d>>1) / 32.0f;                 // 2*(d//2)/64
  float angle = (float)l * powf(10000.0f, -ex);
  pos[tid] = (l & 1) ? cosf(angle) : sinf(angle);
}

// ---- conv3x3 + BN(eval) + leaky_relu (+optional pos-add for the last layer)
__global__ void k_conv3(const float* __restrict__ in, const float* __restrict__ wt,
                        const float* __restrict__ bs, float* __restrict__ out,
                        int Cin, int Cout, const float* __restrict__ pos){
  int idx = blockIdx.x*256 + threadIdx.x;           // F*Cout*256
  int p = idx & 255; int tmp = idx >> 8; int co = tmp % Cout; int f = tmp / Cout;
  int h = p>>4, w = p&15;
  float acc = bs[co];
  const float* wb = wt + co*Cin*9;
  const float* ib = in + f*Cin*256;
  for(int ci=0;ci<Cin;++ci)
    for(int dy=0;dy<3;++dy){ int hh=h+dy-1; if((unsigned)hh>15u) continue;
      for(int dx=0;dx<3;++dx){ int ww=w+dx-1; if((unsigned)ww>15u) continue;
        acc += ib[ci*256+hh*16+ww]*wb[ci*9+dy*3+dx]; } }
  acc = lrelu(acc*BN_INV);
  if(pos) acc += pos[(f>>2)*64 + co];               // f = l*B+b, B=4
  out[idx] = acc;
}

// ---- LayerNorm over (D,H,W)=16384 per (l,b) group
__global__ void k_ln(const float* __restrict__ x, const float* __restrict__ w,
                     const float* __restrict__ b, float* __restrict__ y){
  int g = blockIdx.x, t = threadIdx.x;
  const float* xb = x + g*16384;
  float s=0.f, s2=0.f;
  for(int j=0;j<64;++j){ float v = xb[t + j*256]; s += v; s2 += v*v; }
  __shared__ float ls[256], ls2[256];
  ls[t]=s; ls2[t]=s2; __syncthreads();
  for(int off=128;off>0;off>>=1){ if(t<off){ ls[t]+=ls[t+off]; ls2[t]+=ls2[t+off]; } __syncthreads(); }
  float mu  = ls[0]*(1.0f/16384.f);
  float var = ls2[0]*(1.0f/16384.f) - mu*mu;
  float rinv = rsqrtf(var + 1e-5f);
  float* yb = y + g*16384;
  for(int j=0;j<64;++j){ int e = t + j*256; float v = xb[e];
    yb[e] = (v-mu)*rinv*w[e] + b[e]; }
}

// ---- fused K/V head projections: K,V[b][l][n][k][p]
__global__ void k_kv(const float* __restrict__ y, const float* __restrict__ A,
                     const float* __restrict__ bf, float* __restrict__ K,
                     float* __restrict__ V, int dep){
  int idx = blockIdx.x*256 + threadIdx.x;           // 2,097,152
  int p = idx & 255; int k=(idx>>8)&15; int n=(idx>>12)&3; int l=(idx>>14)&31; int b=idx>>19;
  const float* yb = y + (l*BB+b)*64*256 + p;
  const float* Ak = A + ((dep*2+0)*4+n)*64*16 + k;
  const float* Av = A + ((dep*2+1)*4+n)*64*16 + k;
  float aK = bf[((dep*2+0)*4+n)*16+k];
  float aV = bf[((dep*2+1)*4+n)*16+k];
  for(int d=0;d<64;++d){ float yv = yb[d*256];
    aK += yv*Ak[d*16]; aV += yv*Av[d*16]; }
  K[idx] = aK; V[idx] = aV;                         // idx == (((b*32+l)*4+n)*16+k)*256+p
}

// ---- per-head 5x5 grouped conv on K (LDS-tiled), CK[b][l][n][k][p]
__global__ __launch_bounds__(256) void k_conv5(const float* __restrict__ K,
                       const float* __restrict__ w2, float* __restrict__ CK, int dep){
  __shared__ float tile[16][256];
  int blk = blockIdx.x;                             // (b*32+l)*4+n, 512 blocks
  int n = blk & 3, t = threadIdx.x;
  const float* kb = K + blk*16*256;
  for(int c=0;c<16;++c) tile[c][t] = kb[c*256+t];
  __syncthreads();
  int h = t>>4, w = t&15;
  const float* wb = w2 + (dep*4+n)*16*16*25;
  for(int k=0;k<16;++k){
    float acc = 0.f;
    const float* wk_ = wb + k*400;
    for(int c=0;c<16;++c){
      const float* wc = wk_ + c*25;
      for(int dy=0;dy<5;++dy){ int hh=h+dy-2; if((unsigned)hh>15u) continue;
        const float* tr = &tile[c][hh*16];
        const float* wr = wc + dy*5;
        for(int dx=0;dx<5;++dx){ int ww=w+dx-2; if((unsigned)ww>15u) continue;
          acc += tr[ww]*wr[dx]; } }
    }
    CK[blk*4096 + k*256 + t] = acc;
  }
}

// ---- softmax over L (query-independent!) + weighted V sum -> vout[b][c][p]
__global__ void k_soft(const float* __restrict__ CK, const float* __restrict__ V,
                       float* __restrict__ vout){
  int idx = blockIdx.x*256 + threadIdx.x;           // 65536: (b,n,k,p)
  int p = idx&255; int k=(idx>>8)&15; int n=(idx>>12)&3; int b=idx>>14;
  int base = (b*128 + n)*4096 + k*256 + p;          // l=0; stride over l = 16384
  float e[32]; float m = -1e30f;
  for(int l=0;l<32;++l){ float v = CK[base + l*16384]; e[l]=v; m = fmaxf(m,v); }
  float s = 0.f;
  for(int l=0;l<32;++l){ e[l] = expf(e[l]-m); s += e[l]; }
  float inv = 1.f/s, acc = 0.f;
  for(int l=0;l<32;++l) acc += e[l]*V[base + l*16384];
  vout[((b*4+n)*16+k)*256+p] = acc*inv;
}

// ---- w0 projection + broadcast residual over all L
__global__ void k_w0res(const float* __restrict__ vout, const float* __restrict__ w0,
                        float* __restrict__ xlb, int dep){
  int idx = blockIdx.x*256 + threadIdx.x;           // 65536: (b,o,p)
  int p = idx&255; int o=(idx>>8)&63; int b=idx>>14;
  const float* vb = vout + b*64*256 + p;
  const float* wb = w0 + dep*4096 + o;
  float acc = 0.f;
  for(int c=0;c<64;++c) acc += vb[c*256]*wb[c*64];
  for(int l=0;l<32;++l) xlb[((l*4+b)*64+o)*256 + p] += acc;
}

// ---- feed-forward over the time dimension (32 -> 128 -> 32) + residual
__global__ void k_ff(const float* __restrict__ y, const float* __restrict__ w1,
                     const float* __restrict__ b1, const float* __restrict__ w2,
                     const float* __restrict__ b2, float* __restrict__ xlb, int dep){
  int idx = blockIdx.x*256 + threadIdx.x;           // 65536: (b,d,p)
  int base = idx;                                   // (l=0,b,d,p); stride over l = 65536
  float yv[32];
  for(int l=0;l<32;++l) yv[l] = y[base + l*65536];
  float fa[32];
  for(int l=0;l<32;++l) fa[l] = b2[dep*32+l];
  const float* w1b = w1 + dep*128*32;
  const float* w2b = w2 + dep*32*128;
  for(int m=0;m<128;++m){
    float s = b1[dep*128+m];
    for(int l=0;l<32;++l) s += yv[l]*w1b[m*32+l];
    s = lrelu(s);
    for(int l=0;l<32;++l) fa[l] += s*w2b[l*128+m];
  }
  for(int l=0;l<32;++l) xlb[base + l*65536] += fa[l];
}

extern "C" void kernel_launch(void* const* d_in, const int* in_sizes, int n_in,
                              void* d_out, int out_size, void* d_ws, size_t ws_size,
                              hipStream_t stream) {
  const float* x       = (const float*)d_in[0];
  const float* gw1     = (const float*)d_in[1];
  const float* gb1     = (const float*)d_in[2];
  const float* gw2     = (const float*)d_in[3];
  const float* gb2     = (const float*)d_in[4];
  const float* gw3     = (const float*)d_in[5];
  const float* gb3     = (const float*)d_in[6];
  const float* gw4     = (const float*)d_in[7];
  const float* gb4     = (const float*)d_in[8];
  const float* conv1_w = (const float*)d_in[9];
  const float* conv1_b = (const float*)d_in[10];
  const float* conv2_w = (const float*)d_in[11];
  // d_in[12] = conv2_b : cancels in softmax, unused
  // d_in[13] = wq      : dead code (softmax is query-independent)
  const float* wk      = (const float*)d_in[14];
  const float* wv      = (const float*)d_in[15];
  const float* w0      = (const float*)d_in[16];
  const float* ln1_w   = (const float*)d_in[17];
  const float* ln1_b   = (const float*)d_in[18];
  const float* ln2_w   = (const float*)d_in[19];
  const float* ln2_b   = (const float*)d_in[20];
  const float* ff_w1   = (const float*)d_in[21];
  const float* ff_b1   = (const float*)d_in[22];
  const float* ff_w2   = (const float*)d_in[23];
  const float* ff_b2   = (const float*)d_in[24];

  float* out = (float*)d_out;
  float* ws  = (float*)d_ws;
  float* Y    = ws;                 // 2,097,152
  float* K    = ws + 2097152;       // 2,097,152  (also conv1 intermediate)
  float* CK   = ws + 4194304;       // 2,097,152  (also conv2 intermediate)
  float* V    = ws + 6291456;       // 2,097,152  (also conv3 intermediate)
  float* vout = ws + 8388608;       // 65,536
  float* A    = ws + 8454144;       // 16,384
  float* bf   = ws + 8470528;       // 256
  float* pos  = ws + 8470784;       // 2,048

  k_eff<<<64, 256, 0, stream>>>(conv1_w, conv1_b, wk, wv, A, bf);
  k_pos<<<8, 256, 0, stream>>>(pos);

  // frontend: 3->4->6->8->64 channels, 128 frames
  k_conv3<<<128*4,  256, 0, stream>>>(x,  gw1, gb1, K,   3, 4,  nullptr);
  k_conv3<<<128*6,  256, 0, stream>>>(K,  gw2, gb2, CK,  4, 6,  nullptr);
  k_conv3<<<128*8,  256, 0, stream>>>(CK, gw3, gb3, V,   6, 8,  nullptr);
  k_conv3<<<128*64, 256, 0, stream>>>(V,  gw4, gb4, out, 8, 64, pos);

  for(int dep=0; dep<2; ++dep){
    k_ln   <<<128,  256, 0, stream>>>(out, ln1_w + dep*16384, ln1_b + dep*16384, Y);
    k_kv   <<<8192, 256, 0, stream>>>(Y, A, bf, K, V, dep);
    k_conv5<<<512,  256, 0, stream>>>(K, conv2_w, CK, dep);
    k_soft <<<256,  256, 0, stream>>>(CK, V, vout);
    k_w0res<<<256,  256, 0, stream>>>(vout, w0, out, dep);
    k_ln   <<<128,  256, 0, stream>>>(out, ln2_w + dep*16384, ln2_b + dep*16384, Y);
    k_ff   <<<256,  256, 0, stream>>>(Y, ff_w1, ff_b1, ff_w2, ff_b2, out, dep);
  }
}

// Round 2
// 546.446 us; speedup vs baseline: 1.9782x; 1.9782x over previous
//
#include <hip/hip_runtime.h>
#include <math.h>

#define LL 32
#define BB 4
#define DD 64
#define NH 4
#define DKK 16
#define BN_INV 0.9999950000374997f

__device__ __forceinline__ float lrelu(float v){ return v > 0.f ? v : 0.01f*v; }

// ---- effective per-head K/V projection matrices: A[n][d][k] = sum_c conv1_w[n,(t+1)*64+c,d]*w{k,v}[n,c,k]
__global__ void k_eff(const float* __restrict__ c1w, const float* __restrict__ c1b,
                      const float* __restrict__ wk, const float* __restrict__ wv,
                      float* __restrict__ A, float* __restrict__ bf){
  int tid = blockIdx.x*256 + threadIdx.x;           // 16384 threads
  int k = tid & 15, d = (tid>>4)&63, n=(tid>>10)&3, t=(tid>>12)&1, i=tid>>13;
  const float* wsel = (t ? wv : wk) + (i*NH+n)*64*16;
  const float* cw   = c1w + ((i*NH+n)*192 + (t+1)*64)*64;
  float acc = 0.f;
  for(int c=0;c<64;++c) acc += cw[c*64+d]*wsel[c*16+k];
  A[tid] = acc;                                     // layout (((i*2+t)*4+n)*64+d)*16+k == tid
  if(d==0){
    const float* cb = c1b + (i*NH+n)*192 + (t+1)*64;
    float ba=0.f;
    for(int c=0;c<64;++c) ba += cb[c]*wsel[c*16+k];
    bf[((i*2+t)*4+n)*16+k] = ba;
  }
}

// ---- sinusoidal pos table: pos[l][d]
__global__ void k_pos(float* __restrict__ pos){
  int tid = blockIdx.x*256 + threadIdx.x;           // 2048
  int d = tid & 63, l = tid >> 6;
  float ex = (float)(d>>1) / 32.0f;                 // 2*(d//2)/64
  float angle = (float)l * powf(10000.0f, -ex);
  pos[tid] = (l & 1) ? cosf(angle) : sinf(angle);
}

// ---- transpose conv2 weights to [dep*4+n][c*25+tap][k] for broadcast-friendly reads
__global__ void k_wT(const float* __restrict__ w2, float* __restrict__ wT){
  int tid = blockIdx.x*256 + threadIdx.x;           // 51200
  int k = tid & 15; int rest = tid >> 4;
  int tap = rest % 25; int rest2 = rest / 25;
  int c = rest2 & 15; int dn = rest2 >> 4;          // dep*4+n
  wT[tid] = w2[((dn*16 + k)*16 + c)*25 + tap];
}

// ---- conv3x3 + BN(eval) + leaky_relu (+optional pos-add for the last layer)
__global__ void k_conv3(const float* __restrict__ in, const float* __restrict__ wt,
                        const float* __restrict__ bs, float* __restrict__ out,
                        int Cin, int Cout, const float* __restrict__ pos){
  int idx = blockIdx.x*256 + threadIdx.x;           // F*Cout*256
  int p = idx & 255; int tmp = idx >> 8; int co = tmp % Cout; int f = tmp / Cout;
  int h = p>>4, w = p&15;
  float acc = bs[co];
  const float* wb = wt + co*Cin*9;
  const float* ib = in + f*Cin*256;
  for(int ci=0;ci<Cin;++ci)
    for(int dy=0;dy<3;++dy){ int hh=h+dy-1; if((unsigned)hh>15u) continue;
      for(int dx=0;dx<3;++dx){ int ww=w+dx-1; if((unsigned)ww>15u) continue;
        acc += ib[ci*256+hh*16+ww]*wb[ci*9+dy*3+dx]; } }
  acc = lrelu(acc*BN_INV);
  if(pos) acc += pos[(f>>2)*64 + co];               // f = l*B+b, B=4
  out[idx] = acc;
}

// ---- LayerNorm over (D,H,W)=16384 per (l,b) group
__global__ void k_ln(const float* __restrict__ x, const float* __restrict__ w,
                     const float* __restrict__ b, float* __restrict__ y){
  int g = blockIdx.x, t = threadIdx.x;
  const float* xb = x + g*16384;
  float s=0.f, s2=0.f;
  for(int j=0;j<64;++j){ float v = xb[t + j*256]; s += v; s2 += v*v; }
  __shared__ float ls[256], ls2[256];
  ls[t]=s; ls2[t]=s2; __syncthreads();
  for(int off=128;off>0;off>>=1){ if(t<off){ ls[t]+=ls[t+off]; ls2[t]+=ls2[t+off]; } __syncthreads(); }
  float mu  = ls[0]*(1.0f/16384.f);
  float var = ls2[0]*(1.0f/16384.f) - mu*mu;
  float rinv = rsqrtf(var + 1e-5f);
  float* yb = y + g*16384;
  for(int j=0;j<64;++j){ int e = t + j*256; float v = xb[e];
    yb[e] = (v-mu)*rinv*w[e] + b[e]; }
}

// ---- fused K/V head projections: K,V[b][l][n][k][p]
__global__ void k_kv(const float* __restrict__ y, const float* __restrict__ A,
                     const float* __restrict__ bf, float* __restrict__ K,
                     float* __restrict__ V, int dep){
  int idx = blockIdx.x*256 + threadIdx.x;           // 2,097,152
  int p = idx & 255; int k=(idx>>8)&15; int n=(idx>>12)&3; int l=(idx>>14)&31; int b=idx>>19;
  const float* yb = y + (l*BB+b)*64*256 + p;
  const float* Ak = A + ((dep*2+0)*4+n)*64*16 + k;
  const float* Av = A + ((dep*2+1)*4+n)*64*16 + k;
  float aK = bf[((dep*2+0)*4+n)*16+k];
  float aV = bf[((dep*2+1)*4+n)*16+k];
  for(int d=0;d<64;++d){ float yv = yb[d*256];
    aK += yv*Ak[d*16]; aV += yv*Av[d*16]; }
  K[idx] = aK; V[idx] = aV;                         // idx == (((b*32+l)*4+n)*16+k)*256+p
}

// ---- per-head 5x5 grouped conv on K, register-blocked, zero-padded LDS tile
// grid = 1024: blk = fh*2 + khalf, fh = (b*32+l)*4+n; thread owns pixel t, 8 k-outputs
__global__ __launch_bounds__(256) void k_conv5(const float* __restrict__ K,
                       const float* __restrict__ wT, float* __restrict__ CK, int dep){
  __shared__ float tile[16*400];                    // 16 ch x 20x20, zero border
  int blk = blockIdx.x;
  int khalf = blk & 1; int fh = blk >> 1; int n = fh & 3;
  int t = threadIdx.x;
  const float* kb = K + fh*4096;
  for(int j=t;j<6400;j+=256) tile[j]=0.f;
  __syncthreads();
  int h = t>>4, w = t&15;
  for(int c=0;c<16;++c) tile[c*400 + (h+2)*20 + (w+2)] = kb[c*256+t];
  __syncthreads();
  const float* wb = wT + (dep*4+n)*6400 + khalf*8;
  float acc[8] = {0.f,0.f,0.f,0.f,0.f,0.f,0.f,0.f};
  for(int c=0;c<16;++c){
    const float* tb = tile + c*400 + h*20 + w;      // tap (dy,dx) at tb[dy*20+dx]
    const float* wc = wb + c*400;                   // c*25*16
    #pragma unroll
    for(int dy=0;dy<5;++dy){
      #pragma unroll
      for(int dx=0;dx<5;++dx){
        float v = tb[dy*20+dx];
        const float* wp = wc + (dy*5+dx)*16;
        float4 wa = *(const float4*)(wp);
        float4 wbv = *(const float4*)(wp+4);
        acc[0]+=v*wa.x; acc[1]+=v*wa.y; acc[2]+=v*wa.z; acc[3]+=v*wa.w;
        acc[4]+=v*wbv.x; acc[5]+=v*wbv.y; acc[6]+=v*wbv.z; acc[7]+=v*wbv.w;
      }
    }
  }
  float* ob = CK + fh*4096 + khalf*8*256;
  #pragma unroll
  for(int q=0;q<8;++q) ob[q*256+t] = acc[q];
}

// ---- softmax over L (query-independent!) + weighted V sum -> vout[b][c][p]
__global__ void k_soft(const float* __restrict__ CK, const float* __restrict__ V,
                       float* __restrict__ vout){
  int idx = blockIdx.x*256 + threadIdx.x;           // 65536: (b,n,k,p)
  int p = idx&255; int k=(idx>>8)&15; int n=(idx>>12)&3; int b=idx>>14;
  int base = (b*128 + n)*4096 + k*256 + p;          // l=0; stride over l = 16384
  float e[32]; float m = -1e30f;
  for(int l=0;l<32;++l){ float v = CK[base + l*16384]; e[l]=v; m = fmaxf(m,v); }
  float s = 0.f;
  for(int l=0;l<32;++l){ e[l] = expf(e[l]-m); s += e[l]; }
  float inv = 1.f/s, acc = 0.f;
  for(int l=0;l<32;++l) acc += e[l]*V[base + l*16384];
  vout[((b*4+n)*16+k)*256+p] = acc*inv;
}

// ---- w0 projection + broadcast residual over all L
__global__ void k_w0res(const float* __restrict__ vout, const float* __restrict__ w0,
                        float* __restrict__ xlb, int dep){
  int idx = blockIdx.x*256 + threadIdx.x;           // 65536: (b,o,p)
  int p = idx&255; int o=(idx>>8)&63; int b=idx>>14;
  const float* vb = vout + b*64*256 + p;
  const float* wb = w0 + dep*4096 + o;
  float acc = 0.f;
  for(int c=0;c<64;++c) acc += vb[c*256]*wb[c*64];
  for(int l=0;l<32;++l) xlb[((l*4+b)*64+o)*256 + p] += acc;
}

// ---- feed-forward over the time dimension (32 -> 128 -> 32) + residual
__global__ void k_ff(const float* __restrict__ y, const float* __restrict__ w1,
                     const float* __restrict__ b1, const float* __restrict__ w2,
                     const float* __restrict__ b2, float* __restrict__ xlb, int dep){
  int idx = blockIdx.x*256 + threadIdx.x;           // 65536: (b,d,p)
  int base = idx;                                   // (l=0,b,d,p); stride over l = 65536
  float yv[32];
  for(int l=0;l<32;++l) yv[l] = y[base + l*65536];
  float fa[32];
  for(int l=0;l<32;++l) fa[l] = b2[dep*32+l];
  const float* w1b = w1 + dep*128*32;
  const float* w2b = w2 + dep*32*128;
  for(int m=0;m<128;++m){
    float s = b1[dep*128+m];
    for(int l=0;l<32;++l) s += yv[l]*w1b[m*32+l];
    s = lrelu(s);
    for(int l=0;l<32;++l) fa[l] += s*w2b[l*128+m];
  }
  for(int l=0;l<32;++l) xlb[base + l*65536] += fa[l];
}

extern "C" void kernel_launch(void* const* d_in, const int* in_sizes, int n_in,
                              void* d_out, int out_size, void* d_ws, size_t ws_size,
                              hipStream_t stream) {
  const float* x       = (const float*)d_in[0];
  const float* gw1     = (const float*)d_in[1];
  const float* gb1     = (const float*)d_in[2];
  const float* gw2     = (const float*)d_in[3];
  const float* gb2     = (const float*)d_in[4];
  const float* gw3     = (const float*)d_in[5];
  const float* gb3     = (const float*)d_in[6];
  const float* gw4     = (const float*)d_in[7];
  const float* gb4     = (const float*)d_in[8];
  const float* conv1_w = (const float*)d_in[9];
  const float* conv1_b = (const float*)d_in[10];
  const float* conv2_w = (const float*)d_in[11];
  // d_in[12] = conv2_b : cancels in softmax, unused
  // d_in[13] = wq      : dead code (softmax is query-independent)
  const float* wk      = (const float*)d_in[14];
  const float* wv      = (const float*)d_in[15];
  const float* w0      = (const float*)d_in[16];
  const float* ln1_w   = (const float*)d_in[17];
  const float* ln1_b   = (const float*)d_in[18];
  const float* ln2_w   = (const float*)d_in[19];
  const float* ln2_b   = (const float*)d_in[20];
  const float* ff_w1   = (const float*)d_in[21];
  const float* ff_b1   = (const float*)d_in[22];
  const float* ff_w2   = (const float*)d_in[23];
  const float* ff_b2   = (const float*)d_in[24];

  float* out = (float*)d_out;
  float* ws  = (float*)d_ws;
  float* Y    = ws;                 // 2,097,152
  float* K    = ws + 2097152;       // 2,097,152  (also conv1 intermediate)
  float* CK   = ws + 4194304;       // 2,097,152  (also conv2 intermediate)
  float* V    = ws + 6291456;       // 2,097,152  (also conv3 intermediate)
  float* vout = ws + 8388608;       // 65,536
  float* A    = ws + 8454144;       // 16,384
  float* bf   = ws + 8470528;       // 256
  float* pos  = ws + 8470784;       // 2,048
  float* wT   = ws + 8472832;       // 51,200

  k_eff<<<64, 256, 0, stream>>>(conv1_w, conv1_b, wk, wv, A, bf);
  k_pos<<<8, 256, 0, stream>>>(pos);
  k_wT <<<200, 256, 0, stream>>>(conv2_w, wT);

  // frontend: 3->4->6->8->64 channels, 128 frames
  k_conv3<<<128*4,  256, 0, stream>>>(x,  gw1, gb1, K,   3, 4,  nullptr);
  k_conv3<<<128*6,  256, 0, stream>>>(K,  gw2, gb2, CK,  4, 6,  nullptr);
  k_conv3<<<128*8,  256, 0, stream>>>(CK, gw3, gb3, V,   6, 8,  nullptr);
  k_conv3<<<128*64, 256, 0, stream>>>(V,  gw4, gb4, out, 8, 64, pos);

  for(int dep=0; dep<2; ++dep){
    k_ln   <<<128,  256, 0, stream>>>(out, ln1_w + dep*16384, ln1_b + dep*16384, Y);
    k_kv   <<<8192, 256, 0, stream>>>(Y, A, bf, K, V, dep);
    k_conv5<<<1024, 256, 0, stream>>>(K, wT, CK, dep);
    k_soft <<<256,  256, 0, stream>>>(CK, V, vout);
    k_w0res<<<256,  256, 0, stream>>>(vout, w0, out, dep);
    k_ln   <<<128,  256, 0, stream>>>(out, ln2_w + dep*16384, ln2_b + dep*16384, Y);
    k_ff   <<<256,  256, 0, stream>>>(Y, ff_w1, ff_b1, ff_w2, ff_b2, out, dep);
  }
}

// Round 4
// 469.181 us; speedup vs baseline: 2.3039x; 1.1647x over previous
//
#include <hip/hip_runtime.h>
#include <math.h>

#define LL 32
#define BB 4
#define DD 64
#define NH 4
#define DKK 16
#define BN_INV 0.9999950000374997f

__device__ __forceinline__ float lrelu(float v){ return v > 0.f ? v : 0.01f*v; }

// ---- effective per-head K/V projection matrices: A[n][d][k] = sum_c conv1_w[n,(t+1)*64+c,d]*w{k,v}[n,c,k]
__global__ void k_eff(const float* __restrict__ c1w, const float* __restrict__ c1b,
                      const float* __restrict__ wk, const float* __restrict__ wv,
                      float* __restrict__ A, float* __restrict__ bf){
  int tid = blockIdx.x*256 + threadIdx.x;           // 16384 threads
  int k = tid & 15, d = (tid>>4)&63, n=(tid>>10)&3, t=(tid>>12)&1, i=tid>>13;
  const float* wsel = (t ? wv : wk) + (i*NH+n)*64*16;
  const float* cw   = c1w + ((i*NH+n)*192 + (t+1)*64)*64;
  float acc = 0.f;
  for(int c=0;c<64;++c) acc += cw[c*64+d]*wsel[c*16+k];
  A[tid] = acc;                                     // layout (((i*2+t)*4+n)*64+d)*16+k == tid
  if(d==0){
    const float* cb = c1b + (i*NH+n)*192 + (t+1)*64;
    float ba=0.f;
    for(int c=0;c<64;++c) ba += cb[c]*wsel[c*16+k];
    bf[((i*2+t)*4+n)*16+k] = ba;
  }
}

// ---- sinusoidal pos table: pos[l][d]
__global__ void k_pos(float* __restrict__ pos){
  int tid = blockIdx.x*256 + threadIdx.x;           // 2048
  int d = tid & 63, l = tid >> 6;
  float ex = (float)(d>>1) / 32.0f;                 // 2*(d//2)/64
  float angle = (float)l * powf(10000.0f, -ex);
  pos[tid] = (l & 1) ? cosf(angle) : sinf(angle);
}

// ---- transpose conv2 weights to [dep*4+n][c*25+tap][k] for broadcast-friendly reads
__global__ void k_wT(const float* __restrict__ w2, float* __restrict__ wT){
  int tid = blockIdx.x*256 + threadIdx.x;           // 51200
  int k = tid & 15; int rest = tid >> 4;
  int tap = rest % 25; int rest2 = rest / 25;
  int c = rest2 & 15; int dn = rest2 >> 4;          // dep*4+n
  wT[tid] = w2[((dn*16 + k)*16 + c)*25 + tap];
}

// ---- conv3x3 + BN(eval) + leaky_relu (+optional pos-add for the last layer)
__global__ void k_conv3(const float* __restrict__ in, const float* __restrict__ wt,
                        const float* __restrict__ bs, float* __restrict__ out,
                        int Cin, int Cout, const float* __restrict__ pos){
  int idx = blockIdx.x*256 + threadIdx.x;           // F*Cout*256
  int p = idx & 255; int tmp = idx >> 8; int co = tmp % Cout; int f = tmp / Cout;
  int h = p>>4, w = p&15;
  float acc = bs[co];
  const float* wb = wt + co*Cin*9;
  const float* ib = in + f*Cin*256;
  for(int ci=0;ci<Cin;++ci)
    for(int dy=0;dy<3;++dy){ int hh=h+dy-1; if((unsigned)hh>15u) continue;
      for(int dx=0;dx<3;++dx){ int ww=w+dx-1; if((unsigned)ww>15u) continue;
        acc += ib[ci*256+hh*16+ww]*wb[ci*9+dy*3+dx]; } }
  acc = lrelu(acc*BN_INV);
  if(pos) acc += pos[(f>>2)*64 + co];               // f = l*B+b, B=4
  out[idx] = acc;
}

// ---- LayerNorm over (D,H,W)=16384 per (l,b) group; 1024 threads, float4
__global__ __launch_bounds__(1024) void k_ln(const float* __restrict__ x,
                     const float* __restrict__ w, const float* __restrict__ b,
                     float* __restrict__ y){
  int g = blockIdx.x, t = threadIdx.x;
  const float4* xb = (const float4*)(x + g*16384);
  float4 xv[4];
  float s=0.f, s2=0.f;
  #pragma unroll
  for(int j=0;j<4;++j){
    float4 v = xb[t + j*1024];
    xv[j] = v;
    s  += v.x + v.y + v.z + v.w;
    s2 += v.x*v.x + v.y*v.y + v.z*v.z + v.w*v.w;
  }
  __shared__ float ls[1024], ls2[1024];
  ls[t]=s; ls2[t]=s2; __syncthreads();
  for(int off=512;off>0;off>>=1){
    if(t<off){ ls[t]+=ls[t+off]; ls2[t]+=ls2[t+off]; }
    __syncthreads();
  }
  float mu  = ls[0]*(1.0f/16384.f);
  float var = ls2[0]*(1.0f/16384.f) - mu*mu;
  float rinv = rsqrtf(var + 1e-5f);
  const float4* wb = (const float4*)w;
  const float4* bb = (const float4*)b;
  float4* yb = (float4*)(y + g*16384);
  #pragma unroll
  for(int j=0;j<4;++j){
    int e = t + j*1024;
    float4 v = xv[j], wv = wb[e], bv = bb[e], o;
    o.x = (v.x-mu)*rinv*wv.x + bv.x;
    o.y = (v.y-mu)*rinv*wv.y + bv.y;
    o.z = (v.z-mu)*rinv*wv.z + bv.z;
    o.w = (v.w-mu)*rinv*wv.w + bv.w;
    yb[e] = o;
  }
}

// ---- fused K/V head projections: K,V[b][l][n][k][p]
__global__ void k_kv(const float* __restrict__ y, const float* __restrict__ A,
                     const float* __restrict__ bf, float* __restrict__ K,
                     float* __restrict__ V, int dep){
  int idx = blockIdx.x*256 + threadIdx.x;           // 2,097,152
  int p = idx & 255; int k=(idx>>8)&15; int n=(idx>>12)&3; int l=(idx>>14)&31; int b=idx>>19;
  const float* yb = y + (l*BB+b)*64*256 + p;
  const float* Ak = A + ((dep*2+0)*4+n)*64*16 + k;
  const float* Av = A + ((dep*2+1)*4+n)*64*16 + k;
  float aK = bf[((dep*2+0)*4+n)*16+k];
  float aV = bf[((dep*2+1)*4+n)*16+k];
  for(int d=0;d<64;++d){ float yv = yb[d*256];
    aK += yv*Ak[d*16]; aV += yv*Av[d*16]; }
  K[idx] = aK; V[idx] = aV;                         // idx == (((b*32+l)*4+n)*16+k)*256+p
}

// ---- per-head 5x5 grouped conv on K, register-blocked, zero-padded LDS tile
// grid = 1024: blk = fh*2 + khalf, fh = (b*32+l)*4+n; thread owns pixel t, 8 k-outputs
__global__ __launch_bounds__(256) void k_conv5(const float* __restrict__ K,
                       const float* __restrict__ wT, float* __restrict__ CK, int dep){
  __shared__ float tile[16*400];                    // 16 ch x 20x20, zero border
  int blk = blockIdx.x;
  int khalf = blk & 1; int fh = blk >> 1; int n = fh & 3;
  int t = threadIdx.x;
  const float* kb = K + fh*4096;
  for(int j=t;j<6400;j+=256) tile[j]=0.f;
  __syncthreads();
  int h = t>>4, w = t&15;
  for(int c=0;c<16;++c) tile[c*400 + (h+2)*20 + (w+2)] = kb[c*256+t];
  __syncthreads();
  const float* wb = wT + (dep*4+n)*6400 + khalf*8;
  float acc[8] = {0.f,0.f,0.f,0.f,0.f,0.f,0.f,0.f};
  for(int c=0;c<16;++c){
    const float* tb = tile + c*400 + h*20 + w;      // tap (dy,dx) at tb[dy*20+dx]
    const float* wc = wb + c*400;                   // c*25*16
    #pragma unroll
    for(int dy=0;dy<5;++dy){
      #pragma unroll
      for(int dx=0;dx<5;++dx){
        float v = tb[dy*20+dx];
        const float* wp = wc + (dy*5+dx)*16;
        float4 wa = *(const float4*)(wp);
        float4 wbv = *(const float4*)(wp+4);
        acc[0]+=v*wa.x; acc[1]+=v*wa.y; acc[2]+=v*wa.z; acc[3]+=v*wa.w;
        acc[4]+=v*wbv.x; acc[5]+=v*wbv.y; acc[6]+=v*wbv.z; acc[7]+=v*wbv.w;
      }
    }
  }
  float* ob = CK + fh*4096 + khalf*8*256;
  #pragma unroll
  for(int q=0;q<8;++q) ob[q*256+t] = acc[q];
}

// ---- softmax over L (query-independent!) + weighted V sum -> vout[b][c][p]
__global__ void k_soft(const float* __restrict__ CK, const float* __restrict__ V,
                       float* __restrict__ vout){
  int idx = blockIdx.x*256 + threadIdx.x;           // 65536: (b,n,k,p)
  int p = idx&255; int k=(idx>>8)&15; int n=(idx>>12)&3; int b=idx>>14;
  int base = (b*128 + n)*4096 + k*256 + p;          // l=0; stride over l = 16384
  float e[32]; float m = -1e30f;
  for(int l=0;l<32;++l){ float v = CK[base + l*16384]; e[l]=v; m = fmaxf(m,v); }
  float s = 0.f;
  for(int l=0;l<32;++l){ e[l] = expf(e[l]-m); s += e[l]; }
  float inv = 1.f/s, acc = 0.f;
  for(int l=0;l<32;++l) acc += e[l]*V[base + l*16384];
  vout[((b*4+n)*16+k)*256+p] = acc*inv;
}

// ---- w0 projection + broadcast residual over all L
__global__ void k_w0res(const float* __restrict__ vout, const float* __restrict__ w0,
                        float* __restrict__ xlb, int dep){
  int idx = blockIdx.x*256 + threadIdx.x;           // 65536: (b,o,p)
  int p = idx&255; int o=(idx>>8)&63; int b=idx>>14;
  const float* vb = vout + b*64*256 + p;
  const float* wb = w0 + dep*4096 + o;
  float acc = 0.f;
  for(int c=0;c<64;++c) acc += vb[c*256]*wb[c*64];
  for(int l=0;l<32;++l) xlb[((l*4+b)*64+o)*256 + p] += acc;
}

// ---- feed-forward over the time dimension (32 -> 128 -> 32) + residual
// m-split x4: grid 1024, blk = qblk*4 + mg; LDS-staged 32x32 weight slices;
// partials combined with atomicAdd (4-way same-address).
__global__ __launch_bounds__(256, 4) void k_ff(const float* __restrict__ y,
                     const float* __restrict__ w1, const float* __restrict__ b1,
                     const float* __restrict__ w2, const float* __restrict__ b2,
                     float* __restrict__ xlb, int dep){
  __shared__ float w1s[32*32];                      // [mm][l]
  __shared__ float w2s[32*32];                      // [l][mm]
  int blk = blockIdx.x;
  int mg = blk & 3; int qblk = blk >> 2;
  int t = threadIdx.x;
  const float* w1b = w1 + dep*4096 + mg*32*32;      // w1[m][l], m = mg*32+mm
  const float* w2b = w2 + dep*4096 + mg*32;         // w2[l][m]
  #pragma unroll
  for(int j=0;j<4;++j){
    int e = t + j*256;                              // e = mm*32+l
    w1s[e] = w1b[e];
    int l = e >> 5, mm = e & 31;                    // for w2s[l][mm]
    w2s[e] = w2b[l*128 + mm];
  }
  __syncthreads();
  int base = qblk*256 + t;                          // (b,d,p); stride over l = 65536
  float yv[32];
  #pragma unroll
  for(int l=0;l<32;++l) yv[l] = y[base + l*65536];
  float fa[32];
  if(mg==0){
    #pragma unroll
    for(int l=0;l<32;++l) fa[l] = b2[dep*32+l];
  } else {
    #pragma unroll
    for(int l=0;l<32;++l) fa[l] = 0.f;
  }
  const float* b1b = b1 + dep*128 + mg*32;
  for(int mm=0;mm<32;++mm){
    float s = b1b[mm];
    #pragma unroll
    for(int l=0;l<32;++l) s += yv[l]*w1s[mm*32+l];
    s = lrelu(s);
    #pragma unroll
    for(int l=0;l<32;++l) fa[l] += s*w2s[l*32+mm];
  }
  #pragma unroll
  for(int l=0;l<32;++l) atomicAdd(&xlb[base + l*65536], fa[l]);
}

extern "C" void kernel_launch(void* const* d_in, const int* in_sizes, int n_in,
                              void* d_out, int out_size, void* d_ws, size_t ws_size,
                              hipStream_t stream) {
  const float* x       = (const float*)d_in[0];
  const float* gw1     = (const float*)d_in[1];
  const float* gb1     = (const float*)d_in[2];
  const float* gw2     = (const float*)d_in[3];
  const float* gb2     = (const float*)d_in[4];
  const float* gw3     = (const float*)d_in[5];
  const float* gb3     = (const float*)d_in[6];
  const float* gw4     = (const float*)d_in[7];
  const float* gb4     = (const float*)d_in[8];
  const float* conv1_w = (const float*)d_in[9];
  const float* conv1_b = (const float*)d_in[10];
  const float* conv2_w = (const float*)d_in[11];
  // d_in[12] = conv2_b : cancels in softmax, unused
  // d_in[13] = wq      : dead code (softmax is query-independent)
  const float* wk      = (const float*)d_in[14];
  const float* wv      = (const float*)d_in[15];
  const float* w0      = (const float*)d_in[16];
  const float* ln1_w   = (const float*)d_in[17];
  const float* ln1_b   = (const float*)d_in[18];
  const float* ln2_w   = (const float*)d_in[19];
  const float* ln2_b   = (const float*)d_in[20];
  const float* ff_w1   = (const float*)d_in[21];
  const float* ff_b1   = (const float*)d_in[22];
  const float* ff_w2   = (const float*)d_in[23];
  const float* ff_b2   = (const float*)d_in[24];

  float* out = (float*)d_out;
  float* ws  = (float*)d_ws;
  float* Y    = ws;                 // 2,097,152
  float* K    = ws + 2097152;       // 2,097,152  (also conv1 intermediate)
  float* CK   = ws + 4194304;       // 2,097,152  (also conv2 intermediate)
  float* V    = ws + 6291456;       // 2,097,152  (also conv3 intermediate)
  float* vout = ws + 8388608;       // 65,536
  float* A    = ws + 8454144;       // 16,384
  float* bf   = ws + 8470528;       // 256
  float* pos  = ws + 8470784;       // 2,048
  float* wT   = ws + 8472832;       // 51,200

  k_eff<<<64, 256, 0, stream>>>(conv1_w, conv1_b, wk, wv, A, bf);
  k_pos<<<8, 256, 0, stream>>>(pos);
  k_wT <<<200, 256, 0, stream>>>(conv2_w, wT);

  // frontend: 3->4->6->8->64 channels, 128 frames
  k_conv3<<<128*4,  256, 0, stream>>>(x,  gw1, gb1, K,   3, 4,  nullptr);
  k_conv3<<<128*6,  256, 0, stream>>>(K,  gw2, gb2, CK,  4, 6,  nullptr);
  k_conv3<<<128*8,  256, 0, stream>>>(CK, gw3, gb3, V,   6, 8,  nullptr);
  k_conv3<<<128*64, 256, 0, stream>>>(V,  gw4, gb4, out, 8, 64, pos);

  for(int dep=0; dep<2; ++dep){
    k_ln   <<<128, 1024, 0, stream>>>(out, ln1_w + dep*16384, ln1_b + dep*16384, Y);
    k_kv   <<<8192, 256, 0, stream>>>(Y, A, bf, K, V, dep);
    k_conv5<<<1024, 256, 0, stream>>>(K, wT, CK, dep);
    k_soft <<<256,  256, 0, stream>>>(CK, V, vout);
    k_w0res<<<256,  256, 0, stream>>>(vout, w0, out, dep);
    k_ln   <<<128, 1024, 0, stream>>>(out, ln2_w + dep*16384, ln2_b + dep*16384, Y);
    k_ff   <<<1024, 256, 0, stream>>>(Y, ff_w1, ff_b1, ff_w2, ff_b2, out, dep);
  }
}

// Round 7
// 359.863 us; speedup vs baseline: 3.0038x; 1.3038x over previous
//
#include <hip/hip_runtime.h>
#include <math.h>

#define LL 32
#define BB 4
#define DD 64
#define NH 4
#define DKK 16
#define BN_INV 0.9999950000374997f

__device__ __forceinline__ float lrelu(float v){ return v > 0.f ? v : 0.01f*v; }

// ---- effective per-head K/V projection matrices: A[n][d][k] = sum_c conv1_w[n,(t+1)*64+c,d]*w{k,v}[n,c,k]
__global__ void k_eff(const float* __restrict__ c1w, const float* __restrict__ c1b,
                      const float* __restrict__ wk, const float* __restrict__ wv,
                      float* __restrict__ A, float* __restrict__ bf){
  int tid = blockIdx.x*256 + threadIdx.x;           // 16384 threads
  int k = tid & 15, d = (tid>>4)&63, n=(tid>>10)&3, t=(tid>>12)&1, i=tid>>13;
  const float* wsel = (t ? wv : wk) + (i*NH+n)*64*16;
  const float* cw   = c1w + ((i*NH+n)*192 + (t+1)*64)*64;
  float acc = 0.f;
  for(int c=0;c<64;++c) acc += cw[c*64+d]*wsel[c*16+k];
  A[tid] = acc;                                     // layout (((i*2+t)*4+n)*64+d)*16+k == tid
  if(d==0){
    const float* cb = c1b + (i*NH+n)*192 + (t+1)*64;
    float ba=0.f;
    for(int c=0;c<64;++c) ba += cb[c]*wsel[c*16+k];
    bf[((i*2+t)*4+n)*16+k] = ba;
  }
}

// ---- sinusoidal pos table: pos[l][d]
__global__ void k_pos(float* __restrict__ pos){
  int tid = blockIdx.x*256 + threadIdx.x;           // 2048
  int d = tid & 63, l = tid >> 6;
  float ex = (float)(d>>1) / 32.0f;                 // 2*(d//2)/64
  float angle = (float)l * powf(10000.0f, -ex);
  pos[tid] = (l & 1) ? cosf(angle) : sinf(angle);
}

// ---- transpose conv2 weights to [dep*4+n][c*25+tap][k] for broadcast-friendly reads
__global__ void k_wT(const float* __restrict__ w2, float* __restrict__ wT){
  int tid = blockIdx.x*256 + threadIdx.x;           // 51200
  int k = tid & 15; int rest = tid >> 4;
  int tap = rest % 25; int rest2 = rest / 25;
  int c = rest2 & 15; int dn = rest2 >> 4;          // dep*4+n
  wT[tid] = w2[((dn*16 + k)*16 + c)*25 + tap];
}

// ---- transpose gw4 (64,8,3,3) to wT3[(ci*9+tap)*64 + co]
__global__ void k_wT3(const float* __restrict__ gw4, float* __restrict__ wT3){
  int tid = blockIdx.x*256 + threadIdx.x;           // 4608
  if(tid >= 4608) return;
  int co = tid & 63, ct = tid >> 6;                 // ct = ci*9+tap
  wT3[ct*64 + co] = gw4[co*72 + ct];
}

// ---- fused frontend L1-3: 3->4->6->8 channels, chained zero-padded LDS tiles
// grid = 128 frames, block = 256 px
__global__ __launch_bounds__(256) void k_front(const float* __restrict__ x,
    const float* __restrict__ gw1, const float* __restrict__ gb1,
    const float* __restrict__ gw2, const float* __restrict__ gb2,
    const float* __restrict__ gw3, const float* __restrict__ gb3,
    float* __restrict__ out8){
  __shared__ float sh[4212];                        // t0:3*324 | t1:4*324 | t2:6*324
  float* T0 = sh; float* T1 = sh + 972; float* T2 = sh + 2268;
  int f = blockIdx.x, t = threadIdx.x;
  int h = t>>4, w = t&15;
  for(int j=t;j<4212;j+=256) sh[j]=0.f;
  __syncthreads();
  for(int ci=0;ci<3;++ci) T0[ci*324 + (h+1)*18 + (w+1)] = x[f*768 + ci*256 + t];
  __syncthreads();
  // L1: 3 -> 4
  for(int co=0;co<4;++co){
    float acc = gb1[co];
    for(int ci=0;ci<3;++ci){
      const float* tb = T0 + ci*324 + h*18 + w;
      const float* wb = gw1 + co*27 + ci*9;
      #pragma unroll
      for(int dy=0;dy<3;++dy)
        #pragma unroll
        for(int dx=0;dx<3;++dx) acc += tb[dy*18+dx]*wb[dy*3+dx];
    }
    T1[co*324 + (h+1)*18 + (w+1)] = lrelu(acc*BN_INV);
  }
  __syncthreads();
  // L2: 4 -> 6
  for(int co=0;co<6;++co){
    float acc = gb2[co];
    for(int ci=0;ci<4;++ci){
      const float* tb = T1 + ci*324 + h*18 + w;
      const float* wb = gw2 + co*36 + ci*9;
      #pragma unroll
      for(int dy=0;dy<3;++dy)
        #pragma unroll
        for(int dx=0;dx<3;++dx) acc += tb[dy*18+dx]*wb[dy*3+dx];
    }
    T2[co*324 + (h+1)*18 + (w+1)] = lrelu(acc*BN_INV);
  }
  __syncthreads();
  // L3: 6 -> 8
  for(int co=0;co<8;++co){
    float acc = gb3[co];
    for(int ci=0;ci<6;++ci){
      const float* tb = T2 + ci*324 + h*18 + w;
      const float* wb = gw3 + co*54 + ci*9;
      #pragma unroll
      for(int dy=0;dy<3;++dy)
        #pragma unroll
        for(int dx=0;dx<3;++dx) acc += tb[dy*18+dx]*wb[dy*3+dx];
    }
    out8[f*2048 + co*256 + t] = lrelu(acc*BN_INV);
  }
}

// ---- L4 conv3: 8 -> 64 ch, LDS tile + LDS weights, 16 co per thread, pos-add
// grid = 512: blk = f*4 + g (g = co-group of 16), block = 256 px
__global__ __launch_bounds__(256) void k_conv3_l4(const float* __restrict__ in8,
    const float* __restrict__ wT3, const float* __restrict__ gb4,
    const float* __restrict__ pos, float* __restrict__ out){
  __shared__ float tile[8*324];                     // 8 ch x 18x18 zero-padded
  __shared__ float wsl[1152];                       // [ci*9+tap][16co]
  int blk = blockIdx.x; int g = blk & 3; int f = blk >> 2;
  int t = threadIdx.x; int h = t>>4, w = t&15;
  for(int j=t;j<2592;j+=256) tile[j]=0.f;
  for(int j=t;j<1152;j+=256){
    int ct = j>>4, c16 = j&15;
    wsl[j] = wT3[ct*64 + g*16 + c16];
  }
  __syncthreads();
  for(int ci=0;ci<8;++ci) tile[ci*324 + (h+1)*18 + (w+1)] = in8[f*2048 + ci*256 + t];
  __syncthreads();
  float acc[16];
  #pragma unroll
  for(int q=0;q<16;++q) acc[q] = gb4[g*16+q];
  for(int ci=0;ci<8;++ci){
    const float* tb = tile + ci*324 + h*18 + w;
    #pragma unroll
    for(int dy=0;dy<3;++dy){
      #pragma unroll
      for(int dx=0;dx<3;++dx){
        float v = tb[dy*18+dx];
        const float* wp = wsl + (ci*9+dy*3+dx)*16;
        float4 wa = *(const float4*)(wp);
        float4 wb = *(const float4*)(wp+4);
        float4 wc = *(const float4*)(wp+8);
        float4 wd = *(const float4*)(wp+12);
        acc[0]+=v*wa.x; acc[1]+=v*wa.y; acc[2]+=v*wa.z; acc[3]+=v*wa.w;
        acc[4]+=v*wb.x; acc[5]+=v*wb.y; acc[6]+=v*wb.z; acc[7]+=v*wb.w;
        acc[8]+=v*wc.x; acc[9]+=v*wc.y; acc[10]+=v*wc.z; acc[11]+=v*wc.w;
        acc[12]+=v*wd.x; acc[13]+=v*wd.y; acc[14]+=v*wd.z; acc[15]+=v*wd.w;
      }
    }
  }
  int l = f >> 2;                                   // f = l*B+b
  #pragma unroll
  for(int q=0;q<16;++q){
    float r = lrelu(acc[q]*BN_INV) + pos[l*64 + g*16 + q];
    out[f*16384 + (g*16+q)*256 + t] = r;
  }
}

// ---- LayerNorm over (D,H,W)=16384 per (l,b) group; 1024 threads, float4
__global__ __launch_bounds__(1024) void k_ln(const float* __restrict__ x,
                     const float* __restrict__ w, const float* __restrict__ b,
                     float* __restrict__ y){
  int g = blockIdx.x, t = threadIdx.x;
  const float4* xb = (const float4*)(x + g*16384);
  float4 xv[4];
  float s=0.f, s2=0.f;
  #pragma unroll
  for(int j=0;j<4;++j){
    float4 v = xb[t + j*1024];
    xv[j] = v;
    s  += v.x + v.y + v.z + v.w;
    s2 += v.x*v.x + v.y*v.y + v.z*v.z + v.w*v.w;
  }
  __shared__ float ls[1024], ls2[1024];
  ls[t]=s; ls2[t]=s2; __syncthreads();
  for(int off=512;off>0;off>>=1){
    if(t<off){ ls[t]+=ls[t+off]; ls2[t]+=ls2[t+off]; }
    __syncthreads();
  }
  float mu  = ls[0]*(1.0f/16384.f);
  float var = ls2[0]*(1.0f/16384.f) - mu*mu;
  float rinv = rsqrtf(var + 1e-5f);
  const float4* wb = (const float4*)w;
  const float4* bb = (const float4*)b;
  float4* yb = (float4*)(y + g*16384);
  #pragma unroll
  for(int j=0;j<4;++j){
    int e = t + j*1024;
    float4 v = xv[j], wv = wb[e], bv = bb[e], o;
    o.x = (v.x-mu)*rinv*wv.x + bv.x;
    o.y = (v.y-mu)*rinv*wv.y + bv.y;
    o.z = (v.z-mu)*rinv*wv.z + bv.z;
    o.w = (v.w-mu)*rinv*wv.w + bv.w;
    yb[e] = o;
  }
}

// ---- fused K/V head projections v2: block = (frame lb, head n), thread = pixel
// computes all 16 k for K and V; A-rows are block-uniform (scalar-promotable)
__global__ __launch_bounds__(256) void k_kv(const float* __restrict__ y,
                     const float* __restrict__ A, const float* __restrict__ bf,
                     float* __restrict__ K, float* __restrict__ V, int dep){
  int blk = blockIdx.x;                             // 512: lb*4 + n
  int n = blk & 3; int lb = blk >> 2;               // lb = l*4+b
  int t = threadIdx.x;
  const float* yb  = y + lb*16384 + t;
  const float* akb = A + ((dep*2+0)*4+n)*1024;
  const float* avb = A + ((dep*2+1)*4+n)*1024;
  float kacc[16], vacc[16];
  #pragma unroll
  for(int q=0;q<16;++q){
    kacc[q] = bf[((dep*2+0)*4+n)*16+q];
    vacc[q] = bf[((dep*2+1)*4+n)*16+q];
  }
  for(int d=0;d<64;++d){
    float yv = yb[d*256];
    const float* ak = akb + d*16;
    const float* av = avb + d*16;
    #pragma unroll
    for(int q=0;q<16;++q){ kacc[q] += yv*ak[q]; vacc[q] += yv*av[q]; }
  }
  int l = lb >> 2, b = lb & 3;
  int base = ((b*32+l)*4+n)*4096 + t;               // matches K/V layout
  #pragma unroll
  for(int q=0;q<16;++q){ K[base + q*256] = kacc[q]; V[base + q*256] = vacc[q]; }
}

// ---- per-head 5x5 grouped conv on K, register-blocked, zero-padded LDS tile
// grid = 1024: blk = fh*2 + khalf, fh = (b*32+l)*4+n; thread owns pixel t, 8 k-outputs
__global__ __launch_bounds__(256) void k_conv5(const float* __restrict__ K,
                       const float* __restrict__ wT, float* __restrict__ CK, int dep){
  __shared__ float tile[16*400];                    // 16 ch x 20x20, zero border
  int blk = blockIdx.x;
  int khalf = blk & 1; int fh = blk >> 1; int n = fh & 3;
  int t = threadIdx.x;
  const float* kb = K + fh*4096;
  for(int j=t;j<6400;j+=256) tile[j]=0.f;
  __syncthreads();
  int h = t>>4, w = t&15;
  for(int c=0;c<16;++c) tile[c*400 + (h+2)*20 + (w+2)] = kb[c*256+t];
  __syncthreads();
  const float* wb = wT + (dep*4+n)*6400 + khalf*8;
  float acc[8] = {0.f,0.f,0.f,0.f,0.f,0.f,0.f,0.f};
  for(int c=0;c<16;++c){
    const float* tb = tile + c*400 + h*20 + w;      // tap (dy,dx) at tb[dy*20+dx]
    const float* wc = wb + c*400;                   // c*25*16
    #pragma unroll
    for(int dy=0;dy<5;++dy){
      #pragma unroll
      for(int dx=0;dx<5;++dx){
        float v = tb[dy*20+dx];
        const float* wp = wc + (dy*5+dx)*16;
        float4 wa = *(const float4*)(wp);
        float4 wbv = *(const float4*)(wp+4);
        acc[0]+=v*wa.x; acc[1]+=v*wa.y; acc[2]+=v*wa.z; acc[3]+=v*wa.w;
        acc[4]+=v*wbv.x; acc[5]+=v*wbv.y; acc[6]+=v*wbv.z; acc[7]+=v*wbv.w;
      }
    }
  }
  float* ob = CK + fh*4096 + khalf*8*256;
  #pragma unroll
  for(int q=0;q<8;++q) ob[q*256+t] = acc[q];
}

// ---- softmax over L (query-independent!) + weighted V sum -> vout[b][c][p]
__global__ void k_soft(const float* __restrict__ CK, const float* __restrict__ V,
                       float* __restrict__ vout){
  int idx = blockIdx.x*256 + threadIdx.x;           // 65536: (b,n,k,p)
  int p = idx&255; int k=(idx>>8)&15; int n=(idx>>12)&3; int b=idx>>14;
  int base = (b*128 + n)*4096 + k*256 + p;          // l=0; stride over l = 16384
  float e[32]; float m = -1e30f;
  for(int l=0;l<32;++l){ float v = CK[base + l*16384]; e[l]=v; m = fmaxf(m,v); }
  float s = 0.f;
  for(int l=0;l<32;++l){ e[l] = expf(e[l]-m); s += e[l]; }
  float inv = 1.f/s, acc = 0.f;
  for(int l=0;l<32;++l) acc += e[l]*V[base + l*16384];
  vout[((b*4+n)*16+k)*256+p] = acc*inv;
}

// ---- w0 projection + broadcast residual over all L
__global__ void k_w0res(const float* __restrict__ vout, const float* __restrict__ w0,
                        float* __restrict__ xlb, int dep){
  int idx = blockIdx.x*256 + threadIdx.x;           // 65536: (b,o,p)
  int p = idx&255; int o=(idx>>8)&63; int b=idx>>14;
  const float* vb = vout + b*64*256 + p;
  const float* wb = w0 + dep*4096 + o;
  float acc = 0.f;
  for(int c=0;c<64;++c) acc += vb[c*256]*wb[c*64];
  for(int l=0;l<32;++l) xlb[((l*4+b)*64+o)*256 + p] += acc;
}

// ---- feed-forward over the time dimension (32 -> 128 -> 32) + residual
// m-split x4: grid 1024, blk = qblk*4 + mg; LDS-staged 32x32 weight slices;
// partials combined with atomicAdd (4-way same-address).
__global__ __launch_bounds__(256, 4) void k_ff(const float* __restrict__ y,
                     const float* __restrict__ w1, const float* __restrict__ b1,
                     const float* __restrict__ w2, const float* __restrict__ b2,
                     float* __restrict__ xlb, int dep){
  __shared__ float w1s[32*32];                      // [mm][l]
  __shared__ float w2s[32*32];                      // [l][mm]
  int blk = blockIdx.x;
  int mg = blk & 3; int qblk = blk >> 2;
  int t = threadIdx.x;
  const float* w1b = w1 + dep*4096 + mg*32*32;      // w1[m][l], m = mg*32+mm
  const float* w2b = w2 + dep*4096 + mg*32;         // w2[l][m]
  #pragma unroll
  for(int j=0;j<4;++j){
    int e = t + j*256;                              // e = mm*32+l
    w1s[e] = w1b[e];
    int l = e >> 5, mm = e & 31;                    // for w2s[l][mm]
    w2s[e] = w2b[l*128 + mm];
  }
  __syncthreads();
  int base = qblk*256 + t;                          // (b,d,p); stride over l = 65536
  float yv[32];
  #pragma unroll
  for(int l=0;l<32;++l) yv[l] = y[base + l*65536];
  float fa[32];
  if(mg==0){
    #pragma unroll
    for(int l=0;l<32;++l) fa[l] = b2[dep*32+l];
  } else {
    #pragma unroll
    for(int l=0;l<32;++l) fa[l] = 0.f;
  }
  const float* b1b = b1 + dep*128 + mg*32;
  for(int mm=0;mm<32;++mm){
    float s = b1b[mm];
    #pragma unroll
    for(int l=0;l<32;++l) s += yv[l]*w1s[mm*32+l];
    s = lrelu(s);
    #pragma unroll
    for(int l=0;l<32;++l) fa[l] += s*w2s[l*32+mm];
  }
  #pragma unroll
  for(int l=0;l<32;++l) atomicAdd(&xlb[base + l*65536], fa[l]);
}

extern "C" void kernel_launch(void* const* d_in, const int* in_sizes, int n_in,
                              void* d_out, int out_size, void* d_ws, size_t ws_size,
                              hipStream_t stream) {
  const float* x       = (const float*)d_in[0];
  const float* gw1     = (const float*)d_in[1];
  const float* gb1     = (const float*)d_in[2];
  const float* gw2     = (const float*)d_in[3];
  const float* gb2     = (const float*)d_in[4];
  const float* gw3     = (const float*)d_in[5];
  const float* gb3     = (const float*)d_in[6];
  const float* gw4     = (const float*)d_in[7];
  const float* gb4     = (const float*)d_in[8];
  const float* conv1_w = (const float*)d_in[9];
  const float* conv1_b = (const float*)d_in[10];
  const float* conv2_w = (const float*)d_in[11];
  // d_in[12] = conv2_b : cancels in softmax, unused
  // d_in[13] = wq      : dead code (softmax is query-independent)
  const float* wk      = (const float*)d_in[14];
  const float* wv      = (const float*)d_in[15];
  const float* w0      = (const float*)d_in[16];
  const float* ln1_w   = (const float*)d_in[17];
  const float* ln1_b   = (const float*)d_in[18];
  const float* ln2_w   = (const float*)d_in[19];
  const float* ln2_b   = (const float*)d_in[20];
  const float* ff_w1   = (const float*)d_in[21];
  const float* ff_b1   = (const float*)d_in[22];
  const float* ff_w2   = (const float*)d_in[23];
  const float* ff_b2   = (const float*)d_in[24];

  float* out = (float*)d_out;
  float* ws  = (float*)d_ws;
  float* Y    = ws;                 // 2,097,152
  float* K    = ws + 2097152;       // 2,097,152  (also frontend 8-ch intermediate)
  float* CK   = ws + 4194304;       // 2,097,152
  float* V    = ws + 6291456;       // 2,097,152
  float* vout = ws + 8388608;       // 65,536
  float* A    = ws + 8454144;       // 16,384
  float* bf   = ws + 8470528;       // 256
  float* pos  = ws + 8470784;       // 2,048
  float* wT   = ws + 8472832;       // 51,200
  float* wT3  = ws + 8524032;       // 4,608

  k_eff<<<64, 256, 0, stream>>>(conv1_w, conv1_b, wk, wv, A, bf);
  k_pos<<<8, 256, 0, stream>>>(pos);
  k_wT <<<200, 256, 0, stream>>>(conv2_w, wT);
  k_wT3<<<18, 256, 0, stream>>>(gw4, wT3);

  // frontend: fused 3->4->6->8, then specialized 8->64 with pos-add
  k_front   <<<128, 256, 0, stream>>>(x, gw1, gb1, gw2, gb2, gw3, gb3, K);
  k_conv3_l4<<<512, 256, 0, stream>>>(K, wT3, gb4, pos, out);

  for(int dep=0; dep<2; ++dep){
    k_ln   <<<128, 1024, 0, stream>>>(out, ln1_w + dep*16384, ln1_b + dep*16384, Y);
    k_kv   <<<512,  256, 0, stream>>>(Y, A, bf, K, V, dep);
    k_conv5<<<1024, 256, 0, stream>>>(K, wT, CK, dep);
    k_soft <<<256,  256, 0, stream>>>(CK, V, vout);
    k_w0res<<<256,  256, 0, stream>>>(vout, w0, out, dep);
    k_ln   <<<128, 1024, 0, stream>>>(out, ln2_w + dep*16384, ln2_b + dep*16384, Y);
    k_ff   <<<1024, 256, 0, stream>>>(Y, ff_w1, ff_b1, ff_w2, ff_b2, out, dep);
  }
}